// Round 10
// baseline (22629.446 us; speedup 1.0000x reference)
//
#include <hip/hip_runtime.h>
#include <hip/hip_bf16.h>
#include <stdint.h>

// Problem constants
#define HD   1024
#define BB   32
#define TT   512
#define LL   3
#define H3   3072
#define MTOT (BB*TT)   // 16384

typedef unsigned short u16;
typedef short bf16x8 __attribute__((ext_vector_type(8)));
typedef float f32x4 __attribute__((ext_vector_type(4)));

__device__ __forceinline__ u16 f2bf_bits(float f) {
    __hip_bfloat16 h = __float2bfloat16(f);   // RNE
    return __builtin_bit_cast(u16, h);
}
__device__ __forceinline__ float bf_bits2f(u16 b) {
    return __bfloat162float(__builtin_bit_cast(__hip_bfloat16, b));
}

// 8 consecutive fp32 -> bf16 hi/lo fragments
__device__ __forceinline__ void split8(const f32x4 v0, const f32x4 v1,
                                       bf16x8& hi, bf16x8& lo) {
#pragma unroll
    for (int e = 0; e < 4; ++e) {
        u16 h = f2bf_bits(v0[e]);
        hi[e] = (short)h;
        lo[e] = (short)f2bf_bits(v0[e] - bf_bits2f(h));
        u16 h2 = f2bf_bits(v1[e]);
        hi[4 + e] = (short)h2;
        lo[4 + e] = (short)f2bf_bits(v1[e] - bf_bits2f(h2));
    }
}

// ---------------------------------------------------------------------------
// Split fp32 -> (hi, lo) bf16 planes
__global__ void split_f32_kernel(const float* __restrict__ in,
                                 u16* __restrict__ hi, u16* __restrict__ lo, int n4) {
    int i = blockIdx.x * blockDim.x + threadIdx.x;
    int stride = gridDim.x * blockDim.x;
    for (; i < n4; i += stride) {
        float4 v = ((const float4*)in)[i];
        ushort4 h, l;
        float f;
        f = v.x; h.x = f2bf_bits(f); l.x = f2bf_bits(f - bf_bits2f(h.x));
        f = v.y; h.y = f2bf_bits(f); l.y = f2bf_bits(f - bf_bits2f(h.y));
        f = v.z; h.z = f2bf_bits(f); l.z = f2bf_bits(f - bf_bits2f(h.z));
        f = v.w; h.w = f2bf_bits(f); l.w = f2bf_bits(f - bf_bits2f(h.w));
        ((ushort4*)hi)[i] = h;
        ((ushort4*)lo)[i] = l;
    }
}

// fp32 -> bf16 (hi only)
__global__ void tobf_kernel(const float* __restrict__ in, u16* __restrict__ out, int n4) {
    int i = blockIdx.x * blockDim.x + threadIdx.x;
    int stride = gridDim.x * blockDim.x;
    for (; i < n4; i += stride) {
        float4 v = ((const float4*)in)[i];
        ushort4 h;
        h.x = f2bf_bits(v.x); h.y = f2bf_bits(v.y);
        h.z = f2bf_bits(v.z); h.w = f2bf_bits(v.w);
        ((ushort4*)out)[i] = h;
    }
}

// ---------------------------------------------------------------------------
// 2-pass split-A bf16 MFMA GEMM (layer-0 input projections) — unchanged, proven.
#define BM 128
#define BN 128
#define BK 32
#define LDSROW 40

__global__ __launch_bounds__(256) void gemm2p_kernel(
    const u16* __restrict__ Ahi, const u16* __restrict__ Alo,
    const u16* __restrict__ Wn,
    const float* __restrict__ bias,
    u16* __restrict__ Cout)
{
    __shared__ u16 sAh[BM * LDSROW];
    __shared__ u16 sAl[BM * LDSROW];
    __shared__ u16 sB [BN * LDSROW];

    const int tid  = threadIdx.x;
    const int lane = tid & 63;
    const int w    = tid >> 6;
    const int wr   = w >> 1, wc = w & 1;
    const int fr   = lane & 15;
    const int kg   = lane >> 4;

    const int bm = blockIdx.x & 127;
    const int bn = blockIdx.x >> 7;
    const int bmBase = bm * BM;
    const int bnBase = bn * BN;

    f32x4 acc[4][4] = {};

    for (int kt = 0; kt < 1024; kt += BK) {
        uint4 ra[2], rl[2], rb[2];
#pragma unroll
        for (int it = 0; it < 2; ++it) {
            int c = it * 256 + tid;
            int row = c >> 2, seg = c & 3;
            size_t ga = (size_t)(bmBase + row) * 1024 + kt + seg * 8;
            ra[it] = *(const uint4*)(Ahi + ga);
            rl[it] = *(const uint4*)(Alo + ga);
            size_t gb = (size_t)(bnBase + row) * 1024 + kt + seg * 8;
            rb[it] = *(const uint4*)(Wn + gb);
        }
        __syncthreads();
#pragma unroll
        for (int it = 0; it < 2; ++it) {
            int c = it * 256 + tid;
            int row = c >> 2, seg = c & 3;
            int lo = row * LDSROW + seg * 8;
            *(uint4*)(sAh + lo) = ra[it];
            *(uint4*)(sAl + lo) = rl[it];
            *(uint4*)(sB  + lo) = rb[it];
        }
        __syncthreads();

        bf16x8 fah[4], fal[4], fb[4];
#pragma unroll
        for (int mi = 0; mi < 4; ++mi) {
            int r = wr * 64 + mi * 16 + fr;
            fah[mi] = *(const bf16x8*)(sAh + r * LDSROW + kg * 8);
            fal[mi] = *(const bf16x8*)(sAl + r * LDSROW + kg * 8);
        }
#pragma unroll
        for (int ni = 0; ni < 4; ++ni) {
            int r = wc * 64 + ni * 16 + fr;
            fb[ni] = *(const bf16x8*)(sB + r * LDSROW + kg * 8);
        }
#pragma unroll
        for (int mi = 0; mi < 4; ++mi)
#pragma unroll
            for (int ni = 0; ni < 4; ++ni) {
                acc[mi][ni] = __builtin_amdgcn_mfma_f32_16x16x32_bf16(fah[mi], fb[ni], acc[mi][ni], 0, 0, 0);
                acc[mi][ni] = __builtin_amdgcn_mfma_f32_16x16x32_bf16(fal[mi], fb[ni], acc[mi][ni], 0, 0, 0);
            }
    }

#pragma unroll
    for (int mi = 0; mi < 4; ++mi)
#pragma unroll
        for (int ni = 0; ni < 4; ++ni) {
            int n = bnBase + wc * 64 + ni * 16 + fr;
            float bv = bias[n];
#pragma unroll
            for (int r = 0; r < 4; ++r) {
                int m = bmBase + wr * 64 + mi * 16 + kg * 4 + r;
                int b_ = m >> 9, t_ = m & 511;           // m = b*512 + t
                Cout[(size_t)(t_ * BB + b_) * H3 + n] = f2bf_bits(acc[mi][ni][r] + bv);
            }
        }
}

// ---------------------------------------------------------------------------
// Pipelined per-step kernel. Kernel k computes: layer0 step k, layer1 step
// k-1, layer2 step k-2 (independent within the kernel; kernel boundaries
// provide all cross-XCD ordering/visibility — no custom coherence at all).
// Grid 384 = 3 layers x 128 unit-groups (8 units each); 512 threads = 8 waves
// (K-split 128 each). Weights streamed global->reg (bf16 planes, L2/IC-hot).
// gh = 3-pass split MFMA (hh*wh + hl*wh + hh*wl); gi (layers 1,2) = 2-pass
// (xhh*wi + xhl*wi) from the lower layer's fp32 h, split in-register.
#define SGRID 384

__global__ __launch_bounds__(512) void gru_step_kernel(
    const u16* __restrict__ whhh, const u16* __restrict__ whhl,  // [L][3H][HD]
    const u16* __restrict__ wihh,                                // [L][3H][HD]
    const float* __restrict__ bih, const float* __restrict__ bhh,// [L][3H]
    const u16* __restrict__ gi0,                                 // [T][B][3H] (layer0, incl b_ih)
    float* __restrict__ hb,                                      // [L][2][B][HD] fp32 ping-pong
    float* __restrict__ seqout,                                  // [B][T][HD]
    float* __restrict__ hnout,                                   // [L][B][HD]
    int k)
{
    const int layer = blockIdx.x >> 7;
    const int t = k - layer;
    if (t < 0 || t >= TT) return;
    const int ug = blockIdx.x & 127;
    const int n0 = ug * 8;
    const int tid = threadIdx.x, lane = tid & 63, w = tid >> 6;
    const int arow = lane & 15, akg = lane >> 4;

    __shared__ float Cp[2][2][2][16][16];   // [src][m][nt][row][col] 8KB

    ((float*)Cp)[tid]        = 0.f;
    ((float*)Cp)[tid + 512]  = 0.f;
    ((float*)Cp)[tid + 1024] = 0.f;
    ((float*)Cp)[tid + 1536] = 0.f;

    const float* hown = hb + ((size_t)layer * 2 + (t & 1)) * BB * HD;
    const float* xin  = hb + ((size_t)(layer - 1) * 2 + ((t + 1) & 1)) * BB * HD;

    // layer-0 gi prefetch (plain loads; compiler schedules/waits)
    float gi_0 = 0.f, gi_1 = 0.f, gi_2 = 0.f;
    if (layer == 0 && tid < 256) {
        const u16* gp = gi0 + (size_t)(t * BB + (tid >> 3)) * H3 + n0 + (tid & 7);
        gi_0 = bf_bits2f(gp[0]);
        gi_1 = bf_bits2f(gp[HD]);
        gi_2 = bf_bits2f(gp[2 * HD]);
    }
    __syncthreads();   // Cp zeros visible

    const size_t wbase = (size_t)layer * H3 * HD;

    f32x4 agh[2][2] = {};
    f32x4 agi[2][2] = {};

#pragma unroll
    for (int kt = 0; kt < 4; ++kt) {
        const int k0 = w * 128 + kt * 32 + akg * 8;

        // A fragments: own h (fp32 -> hi/lo bf16)
        bf16x8 ahh[2], ahl[2];
#pragma unroll
        for (int m = 0; m < 2; ++m) {
            const float* p = hown + (size_t)(m * 16 + arow) * HD + k0;
            f32x4 v0 = *(const f32x4*)p;
            f32x4 v1 = *(const f32x4*)(p + 4);
            split8(v0, v1, ahh[m], ahl[m]);
        }
        // B fragments: w_hh hi/lo (rows j>=24 are pad -> zero)
        bf16x8 bh_[2] = {}, bl_[2] = {};
#pragma unroll
        for (int nt = 0; nt < 2; ++nt) {
            int j = nt * 16 + arow;
            if (j < 24) {
                size_t ro = wbase + ((size_t)(j >> 3) * HD + n0 + (j & 7)) * HD + k0;
                bh_[nt] = *(const bf16x8*)(whhh + ro);
                bl_[nt] = *(const bf16x8*)(whhl + ro);
            }
        }
#pragma unroll
        for (int m = 0; m < 2; ++m)
#pragma unroll
            for (int nt = 0; nt < 2; ++nt) {
                agh[m][nt] = __builtin_amdgcn_mfma_f32_16x16x32_bf16(ahh[m], bh_[nt], agh[m][nt], 0, 0, 0);
                agh[m][nt] = __builtin_amdgcn_mfma_f32_16x16x32_bf16(ahl[m], bh_[nt], agh[m][nt], 0, 0, 0);
                agh[m][nt] = __builtin_amdgcn_mfma_f32_16x16x32_bf16(ahh[m], bl_[nt], agh[m][nt], 0, 0, 0);
            }

        if (layer > 0) {
            // gi on the fly: x = lower layer's h(t) output (fp32)
            bf16x8 xhh[2], xhl[2];
#pragma unroll
            for (int m = 0; m < 2; ++m) {
                const float* p = xin + (size_t)(m * 16 + arow) * HD + k0;
                f32x4 v0 = *(const f32x4*)p;
                f32x4 v1 = *(const f32x4*)(p + 4);
                split8(v0, v1, xhh[m], xhl[m]);
            }
            bf16x8 bi_[2] = {};
#pragma unroll
            for (int nt = 0; nt < 2; ++nt) {
                int j = nt * 16 + arow;
                if (j < 24) {
                    size_t ro = wbase + ((size_t)(j >> 3) * HD + n0 + (j & 7)) * HD + k0;
                    bi_[nt] = *(const bf16x8*)(wihh + ro);
                }
            }
#pragma unroll
            for (int m = 0; m < 2; ++m)
#pragma unroll
                for (int nt = 0; nt < 2; ++nt) {
                    agi[m][nt] = __builtin_amdgcn_mfma_f32_16x16x32_bf16(xhh[m], bi_[nt], agi[m][nt], 0, 0, 0);
                    agi[m][nt] = __builtin_amdgcn_mfma_f32_16x16x32_bf16(xhl[m], bi_[nt], agi[m][nt], 0, 0, 0);
                }
        }
    }

    // K-slice reduction (LDS atomics — proven path; acc row=(lane>>4)*4+i, col=lane&15)
#pragma unroll
    for (int m = 0; m < 2; ++m)
#pragma unroll
        for (int nt = 0; nt < 2; ++nt)
#pragma unroll
            for (int i = 0; i < 4; ++i)
                atomicAdd(&Cp[0][m][nt][akg * 4 + i][arow], agh[m][nt][i]);
    if (layer > 0) {
#pragma unroll
        for (int m = 0; m < 2; ++m)
#pragma unroll
            for (int nt = 0; nt < 2; ++nt)
#pragma unroll
                for (int i = 0; i < 4; ++i)
                    atomicAdd(&Cp[1][m][nt][akg * 4 + i][arow], agi[m][nt][i]);
    }
    __syncthreads();

    // Gate phase: 256 threads, one (b,u) each
    if (tid < 256) {
        const int b = tid >> 3, u = tid & 7;
        const int m = b >> 4, r = b & 15;
        float gh0 = Cp[0][m][0][r][u];
        float gh1 = Cp[0][m][0][r][8 + u];
        float gh2 = Cp[0][m][1][r][u];
        if (layer > 0) {
            gi_0 = Cp[1][m][0][r][u]      + bih[layer * H3 + n0 + u];
            gi_1 = Cp[1][m][0][r][8 + u]  + bih[layer * H3 + HD + n0 + u];
            gi_2 = Cp[1][m][1][r][u]      + bih[layer * H3 + 2 * HD + n0 + u];
        }
        float bh0 = bhh[layer * H3 + n0 + u];
        float bh1 = bhh[layer * H3 + HD + n0 + u];
        float bh2 = bhh[layer * H3 + 2 * HD + n0 + u];
        float hp = hown[(size_t)b * HD + n0 + u];
        float rg = 1.f / (1.f + expf(-(gi_0 + gh0 + bh0)));
        float zg = 1.f / (1.f + expf(-(gi_1 + gh1 + bh1)));
        float ng = tanhf(gi_2 + rg * (gh2 + bh2));
        float hnew = (1.f - zg) * ng + zg * hp;
        hb[((size_t)layer * 2 + ((t + 1) & 1)) * BB * HD + (size_t)b * HD + n0 + u] = hnew;
        if (layer == 2) seqout[((size_t)b * TT + t) * HD + n0 + u] = hnew;
        if (t == TT - 1) hnout[(size_t)layer * BB * HD + (size_t)b * HD + n0 + u] = hnew;
    }
}

// ---------------------------------------------------------------------------
extern "C" void kernel_launch(void* const* d_in, const int* in_sizes, int n_in,
                              void* d_out, int out_size, void* d_ws, size_t ws_size,
                              hipStream_t stream) {
    const float* x   = (const float*)d_in[0];
    const float* h0  = (const float*)d_in[1];
    const float* wih = (const float*)d_in[2];
    const float* whh = (const float*)d_in[3];
    const float* bih = (const float*)d_in[4];
    const float* bhh = (const float*)d_in[5];
    float* out = (float*)d_out;

    char* ws = (char*)d_ws;
    size_t off = 0;
    auto alloc = [&](size_t bytes) -> void* {
        void* p = ws + off;
        off += (bytes + 255) & ~(size_t)255;
        return p;
    };
    // ~217.5 MB total (well under the R6 overflow point)
    u16* gi   = (u16*)alloc((size_t)MTOT * H3 * 2);        // 96 MB (layer0 gi)
    u16* p0h  = (u16*)alloc((size_t)MTOT * HD * 2);        // 32 MB (x hi)
    u16* p0l  = (u16*)alloc((size_t)MTOT * HD * 2);        // 32 MB (x lo)
    u16* wihb = (u16*)alloc((size_t)LL * H3 * HD * 2);     // 18.9 MB (w_ih bf16)
    u16* whhh = (u16*)alloc((size_t)LL * H3 * HD * 2);     // 18.9 MB (w_hh hi)
    u16* whhl = (u16*)alloc((size_t)LL * H3 * HD * 2);     // 18.9 MB (w_hh lo)
    float* hb = (float*)alloc((size_t)LL * 2 * BB * HD * 4); // 768 KB ping-pong

    // setup: splits + h0 staging
    split_f32_kernel<<<2048, 256, 0, stream>>>(x, p0h, p0l, MTOT * HD / 4);
    split_f32_kernel<<<2048, 256, 0, stream>>>(whh, whhh, whhl, LL * H3 * HD / 4);
    tobf_kernel<<<2048, 256, 0, stream>>>(wih, wihb, LL * H3 * HD / 4);
    for (int l = 0; l < LL; ++l)
        hipMemcpyAsync(hb + (size_t)l * 2 * BB * HD, h0 + (size_t)l * BB * HD,
                       (size_t)BB * HD * 4, hipMemcpyDeviceToDevice, stream);

    float* seqbase = out;                        // [B][T][H]
    float* hnbase  = out + (size_t)BB * TT * HD; // [L][B][H]

    // layer-0 input projections (one big GEMM)
    gemm2p_kernel<<<dim3(128 * 24), 256, 0, stream>>>(p0h, p0l, wihb, bih, gi);

    // pipelined recurrence: 514 step kernels
    for (int k = 0; k < TT + LL - 1; ++k)
        gru_step_kernel<<<SGRID, 512, 0, stream>>>(
            whhh, whhl, wihb, bih, bhh, gi, hb, seqbase, hnbase, k);
}

// Round 11
// 9466.238 us; speedup vs baseline: 2.3905x; 2.3905x over previous
//
#include <hip/hip_runtime.h>
#include <hip/hip_bf16.h>
#include <stdint.h>

// Problem constants
#define HD   1024
#define BB   32
#define TT   512
#define LL   3
#define H3   3072
#define MTOT (BB*TT)   // 16384

#define PLSZ 32768     // u16 per h plane: 128 kc x 32 b x 8
#define WSL  16384     // u16 per weight slab plane: 128 kc x 16 j x 8

typedef unsigned short u16;
typedef short bf16x8 __attribute__((ext_vector_type(8)));
typedef float f32x4 __attribute__((ext_vector_type(4)));

__device__ __forceinline__ u16 f2bf_bits(float f) {
    __hip_bfloat16 h = __float2bfloat16(f);   // RNE
    return __builtin_bit_cast(u16, h);
}
__device__ __forceinline__ float bf_bits2f(u16 b) {
    return __bfloat162float(__builtin_bit_cast(__hip_bfloat16, b));
}

// 8 consecutive fp32 -> bf16 hi/lo fragments
__device__ __forceinline__ void split8(const f32x4 v0, const f32x4 v1,
                                       bf16x8& hi, bf16x8& lo) {
#pragma unroll
    for (int e = 0; e < 4; ++e) {
        u16 h = f2bf_bits(v0[e]);
        hi[e] = (short)h;
        lo[e] = (short)f2bf_bits(v0[e] - bf_bits2f(h));
        u16 h2 = f2bf_bits(v1[e]);
        hi[4 + e] = (short)h2;
        lo[4 + e] = (short)f2bf_bits(v1[e] - bf_bits2f(h2));
    }
}

// ---------------------------------------------------------------------------
// Split fp32 -> (hi, lo) bf16 planes (row-major, for the big GEMM)
__global__ void split_f32_kernel(const float* __restrict__ in,
                                 u16* __restrict__ hi, u16* __restrict__ lo, int n4) {
    int i = blockIdx.x * blockDim.x + threadIdx.x;
    int stride = gridDim.x * blockDim.x;
    for (; i < n4; i += stride) {
        float4 v = ((const float4*)in)[i];
        ushort4 h, l;
        float f;
        f = v.x; h.x = f2bf_bits(f); l.x = f2bf_bits(f - bf_bits2f(h.x));
        f = v.y; h.y = f2bf_bits(f); l.y = f2bf_bits(f - bf_bits2f(h.y));
        f = v.z; h.z = f2bf_bits(f); l.z = f2bf_bits(f - bf_bits2f(h.z));
        f = v.w; h.w = f2bf_bits(f); l.w = f2bf_bits(f - bf_bits2f(h.w));
        ((ushort4*)hi)[i] = h;
        ((ushort4*)lo)[i] = l;
    }
}

// fp32 -> bf16 (hi only)
__global__ void tobf_kernel(const float* __restrict__ in, u16* __restrict__ out, int n4) {
    int i = blockIdx.x * blockDim.x + threadIdx.x;
    int stride = gridDim.x * blockDim.x;
    for (; i < n4; i += stride) {
        float4 v = ((const float4*)in)[i];
        ushort4 h;
        h.x = f2bf_bits(v.x); h.y = f2bf_bits(v.y);
        h.z = f2bf_bits(v.z); h.w = f2bf_bits(v.w);
        ((ushort4*)out)[i] = h;
    }
}

// ---------------------------------------------------------------------------
// Pack per-(layer,ug) weight slabs in MFMA fragment order [kc][16 j][8]:
// j = gate*4 + u (12 real rows + 4 zero pad). whh -> hi/lo planes; wih -> hi.
__global__ __launch_bounds__(256) void pack_w_kernel(
    const float* __restrict__ whh, const float* __restrict__ wih,
    u16* __restrict__ wslab, u16* __restrict__ wislab)
{
    const int l  = blockIdx.x >> 8;
    const int ug = blockIdx.x & 255;
    const int n0 = ug * 4;
    const int tid = threadIdx.x;
    const int j = tid >> 4, c16 = tid & 15;
    const bool real = (j < 12);
    const size_t rowoff = real ? ((size_t)(j >> 2) * HD + n0 + (j & 3)) * HD : 0;
    const float* wh = whh + (size_t)l * H3 * HD;
    const float* wi = wih + (size_t)l * H3 * HD;
    u16* dh = wslab + (((size_t)l * 256 + ug) * 2) * WSL;
    u16* dl = dh + WSL;
    u16* di = (l > 0) ? (wislab + ((size_t)(l - 1) * 256 + ug) * WSL) : (u16*)nullptr;
#pragma unroll
    for (int c = 0; c < 8; ++c) {
        int kc = c16 + c * 16;
        bf16x8 hi = {}, lo = {}, ihi = {};
        if (real) {
            f32x4 v0 = *(const f32x4*)(wh + rowoff + kc * 8);
            f32x4 v1 = *(const f32x4*)(wh + rowoff + kc * 8 + 4);
            split8(v0, v1, hi, lo);
            if (l > 0) {
                f32x4 u0 = *(const f32x4*)(wi + rowoff + kc * 8);
                f32x4 u1 = *(const f32x4*)(wi + rowoff + kc * 8 + 4);
                bf16x8 dum;
                split8(u0, u1, ihi, dum);
            }
        }
        int off = (kc * 16 + j) * 8;
        *(bf16x8*)(dh + off) = hi;
        *(bf16x8*)(dl + off) = lo;
        if (l > 0) *(bf16x8*)(di + off) = ihi;
    }
}

// h0 -> fp32 ping-pong (parity 0) + transposed bf16 hi/lo planes (parity 0)
__global__ void pack_h0_kernel(const float* __restrict__ h0,
                               float* __restrict__ hb, u16* __restrict__ ht) {
    int idx = blockIdx.x * 256 + threadIdx.x;   // 3*32*1024 total
    int l = idx >> 15;
    int rem = idx & 32767;
    int b = rem >> 10, n = rem & 1023;
    float f = h0[idx];
    hb[(size_t)(l * 2) * BB * HD + rem] = f;
    u16 hbits = f2bf_bits(f);
    u16 lbits = f2bf_bits(f - bf_bits2f(hbits));
    size_t o = ((size_t)(l * 2) * 2) * PLSZ + ((size_t)(n >> 3) * 32 + b) * 8 + (n & 7);
    ht[o] = hbits;
    ht[o + PLSZ] = lbits;
}

// ---------------------------------------------------------------------------
// 2-pass split-A bf16 MFMA GEMM (layer-0 input projections) — unchanged, proven.
#define BM 128
#define BN 128
#define BK 32
#define LDSROW 40

__global__ __launch_bounds__(256) void gemm2p_kernel(
    const u16* __restrict__ Ahi, const u16* __restrict__ Alo,
    const u16* __restrict__ Wn,
    const float* __restrict__ bias,
    u16* __restrict__ Cout)
{
    __shared__ u16 sAh[BM * LDSROW];
    __shared__ u16 sAl[BM * LDSROW];
    __shared__ u16 sB [BN * LDSROW];

    const int tid  = threadIdx.x;
    const int lane = tid & 63;
    const int w    = tid >> 6;
    const int wr   = w >> 1, wc = w & 1;
    const int fr   = lane & 15;
    const int kg   = lane >> 4;

    const int bm = blockIdx.x & 127;
    const int bn = blockIdx.x >> 7;
    const int bmBase = bm * BM;
    const int bnBase = bn * BN;

    f32x4 acc[4][4] = {};

    for (int kt = 0; kt < 1024; kt += BK) {
        uint4 ra[2], rl[2], rb[2];
#pragma unroll
        for (int it = 0; it < 2; ++it) {
            int c = it * 256 + tid;
            int row = c >> 2, seg = c & 3;
            size_t ga = (size_t)(bmBase + row) * 1024 + kt + seg * 8;
            ra[it] = *(const uint4*)(Ahi + ga);
            rl[it] = *(const uint4*)(Alo + ga);
            size_t gb = (size_t)(bnBase + row) * 1024 + kt + seg * 8;
            rb[it] = *(const uint4*)(Wn + gb);
        }
        __syncthreads();
#pragma unroll
        for (int it = 0; it < 2; ++it) {
            int c = it * 256 + tid;
            int row = c >> 2, seg = c & 3;
            int lo = row * LDSROW + seg * 8;
            *(uint4*)(sAh + lo) = ra[it];
            *(uint4*)(sAl + lo) = rl[it];
            *(uint4*)(sB  + lo) = rb[it];
        }
        __syncthreads();

        bf16x8 fah[4], fal[4], fb[4];
#pragma unroll
        for (int mi = 0; mi < 4; ++mi) {
            int r = wr * 64 + mi * 16 + fr;
            fah[mi] = *(const bf16x8*)(sAh + r * LDSROW + kg * 8);
            fal[mi] = *(const bf16x8*)(sAl + r * LDSROW + kg * 8);
        }
#pragma unroll
        for (int ni = 0; ni < 4; ++ni) {
            int r = wc * 64 + ni * 16 + fr;
            fb[ni] = *(const bf16x8*)(sB + r * LDSROW + kg * 8);
        }
#pragma unroll
        for (int mi = 0; mi < 4; ++mi)
#pragma unroll
            for (int ni = 0; ni < 4; ++ni) {
                acc[mi][ni] = __builtin_amdgcn_mfma_f32_16x16x32_bf16(fah[mi], fb[ni], acc[mi][ni], 0, 0, 0);
                acc[mi][ni] = __builtin_amdgcn_mfma_f32_16x16x32_bf16(fal[mi], fb[ni], acc[mi][ni], 0, 0, 0);
            }
    }

#pragma unroll
    for (int mi = 0; mi < 4; ++mi)
#pragma unroll
        for (int ni = 0; ni < 4; ++ni) {
            int n = bnBase + wc * 64 + ni * 16 + fr;
            float bv = bias[n];
#pragma unroll
            for (int r = 0; r < 4; ++r) {
                int m = bmBase + wr * 64 + mi * 16 + kg * 4 + r;
                int b_ = m >> 9, t_ = m & 511;           // m = b*512 + t
                Cout[(size_t)(t_ * BB + b_) * H3 + n] = f2bf_bits(acc[mi][ni][r] + bv);
            }
        }
}

// ---------------------------------------------------------------------------
// Pipelined per-step kernel. Kernel k: layer0 step k, layer1 k-1, layer2 k-2.
// Kernel boundaries provide all cross-XCD ordering (no custom coherence).
// Grid 768 = 3 layers x 256 ug (4 units); 256 threads = 4 waves (K-split 256).
// All weight/h fragments are CONTIGUOUS packed loads (slab [kc][j][8], h plane
// [kc][b][8]); h hi/lo planes produced once by the previous step's gate phase.
#define SGRID 768

__global__ __launch_bounds__(256) void gru_step_kernel(
    const u16* __restrict__ wslab,   // [3][256][2][WSL]
    const u16* __restrict__ wislab,  // [2][256][WSL] (layers 1,2)
    const float* __restrict__ bih, const float* __restrict__ bhh,  // [L][3H]
    const u16* __restrict__ gi0,     // [T][B][3H] (layer0, incl b_ih)
    float* __restrict__ hb,          // [3][2][32][1024] fp32
    u16* __restrict__ ht,            // [3][2][2][PLSZ] transposed planes
    float* __restrict__ seqout, float* __restrict__ hnout, int k)
{
    const int layer = blockIdx.x >> 8;
    const int t = k - layer;
    if (t < 0 || t >= TT) return;
    const int ug = blockIdx.x & 255;
    const int n0 = ug * 4;
    const int tid = threadIdx.x, lane = tid & 63, w = tid >> 6;
    const int arow = lane & 15, akg = lane >> 4;

    __shared__ float Cp[4][2][2][16][16];   // [wave][src][m][row][col] 16KB

    const int xl = (layer > 0) ? layer - 1 : 0;
    const u16* hsH = ht + ((size_t)(layer * 2 + (t & 1)) * 2) * PLSZ;
    const u16* hsL = hsH + PLSZ;
    const u16* xsH = ht + ((size_t)(xl * 2 + ((t + 1) & 1)) * 2) * PLSZ;
    const u16* xsL = xsH + PLSZ;
    const u16* whH = wslab + (((size_t)layer * 256 + ug) * 2) * WSL;
    const u16* whL = whH + WSL;
    const u16* wiH = wislab + ((size_t)((layer > 0 ? layer - 1 : 0)) * 256 + ug) * WSL;

    // layer-0 gi early loads (latency hidden under the MFMA loop)
    float gi_0 = 0.f, gi_1 = 0.f, gi_2 = 0.f;
    if (layer == 0 && tid < 128) {
        const u16* gp = gi0 + (size_t)(t * BB + (tid >> 2)) * H3 + n0 + (tid & 3);
        gi_0 = bf_bits2f(gp[0]);
        gi_1 = bf_bits2f(gp[HD]);
        gi_2 = bf_bits2f(gp[2 * HD]);
    }

    f32x4 agh[2] = {};
    f32x4 agx[2] = {};

#pragma unroll
    for (int kt = 0; kt < 8; ++kt) {
        const int kc = w * 32 + kt * 4 + akg;
        const int aoff = (kc * 32 + arow) * 8;     // m=0; m=1 at +128
        const int woff = (kc * 16 + arow) * 8;
        bf16x8 a0h = *(const bf16x8*)(hsH + aoff);
        bf16x8 a0l = *(const bf16x8*)(hsL + aoff);
        bf16x8 a1h = *(const bf16x8*)(hsH + aoff + 128);
        bf16x8 a1l = *(const bf16x8*)(hsL + aoff + 128);
        bf16x8 bh  = *(const bf16x8*)(whH + woff);
        bf16x8 bl  = *(const bf16x8*)(whL + woff);
        agh[0] = __builtin_amdgcn_mfma_f32_16x16x32_bf16(a0h, bh, agh[0], 0, 0, 0);
        agh[0] = __builtin_amdgcn_mfma_f32_16x16x32_bf16(a0l, bh, agh[0], 0, 0, 0);
        agh[0] = __builtin_amdgcn_mfma_f32_16x16x32_bf16(a0h, bl, agh[0], 0, 0, 0);
        agh[1] = __builtin_amdgcn_mfma_f32_16x16x32_bf16(a1h, bh, agh[1], 0, 0, 0);
        agh[1] = __builtin_amdgcn_mfma_f32_16x16x32_bf16(a1l, bh, agh[1], 0, 0, 0);
        agh[1] = __builtin_amdgcn_mfma_f32_16x16x32_bf16(a1h, bl, agh[1], 0, 0, 0);
        if (layer > 0) {
            bf16x8 x0h = *(const bf16x8*)(xsH + aoff);
            bf16x8 x0l = *(const bf16x8*)(xsL + aoff);
            bf16x8 x1h = *(const bf16x8*)(xsH + aoff + 128);
            bf16x8 x1l = *(const bf16x8*)(xsL + aoff + 128);
            bf16x8 bi  = *(const bf16x8*)(wiH + woff);
            agx[0] = __builtin_amdgcn_mfma_f32_16x16x32_bf16(x0h, bi, agx[0], 0, 0, 0);
            agx[0] = __builtin_amdgcn_mfma_f32_16x16x32_bf16(x0l, bi, agx[0], 0, 0, 0);
            agx[1] = __builtin_amdgcn_mfma_f32_16x16x32_bf16(x1h, bi, agx[1], 0, 0, 0);
            agx[1] = __builtin_amdgcn_mfma_f32_16x16x32_bf16(x1l, bi, agx[1], 0, 0, 0);
        }
    }

    // Per-wave partial slices (no atomics): full coverage, no zero-init needed.
#pragma unroll
    for (int m = 0; m < 2; ++m)
#pragma unroll
        for (int i = 0; i < 4; ++i)
            Cp[w][0][m][akg * 4 + i][arow] = agh[m][i];
    if (layer > 0) {
#pragma unroll
        for (int m = 0; m < 2; ++m)
#pragma unroll
            for (int i = 0; i < 4; ++i)
                Cp[w][1][m][akg * 4 + i][arow] = agx[m][i];
    }
    __syncthreads();

    // Gate phase: 128 threads, one (b,u) each
    if (tid < 128) {
        const int b = tid >> 2, u = tid & 3;
        const int m = b >> 4, r = b & 15;
        const int n = n0 + u;
        float gh0 = 0.f, gh1 = 0.f, gh2 = 0.f;
#pragma unroll
        for (int ww = 0; ww < 4; ++ww) {
            gh0 += Cp[ww][0][m][r][u];
            gh1 += Cp[ww][0][m][r][4 + u];
            gh2 += Cp[ww][0][m][r][8 + u];
        }
        if (layer > 0) {
            float q0 = 0.f, q1 = 0.f, q2 = 0.f;
#pragma unroll
            for (int ww = 0; ww < 4; ++ww) {
                q0 += Cp[ww][1][m][r][u];
                q1 += Cp[ww][1][m][r][4 + u];
                q2 += Cp[ww][1][m][r][8 + u];
            }
            gi_0 = q0 + bih[layer * H3 + n];
            gi_1 = q1 + bih[layer * H3 + HD + n];
            gi_2 = q2 + bih[layer * H3 + 2 * HD + n];
        }
        const float bh0 = bhh[layer * H3 + n];
        const float bh1 = bhh[layer * H3 + HD + n];
        const float bh2 = bhh[layer * H3 + 2 * HD + n];
        const float hp = hb[(size_t)(layer * 2 + (t & 1)) * BB * HD + (size_t)b * HD + n];
        float rg = 1.f / (1.f + expf(-(gi_0 + gh0 + bh0)));
        float zg = 1.f / (1.f + expf(-(gi_1 + gh1 + bh1)));
        float ng = tanhf(gi_2 + rg * (gh2 + bh2));
        float hnew = (1.f - zg) * ng + zg * hp;
        hb[(size_t)(layer * 2 + ((t + 1) & 1)) * BB * HD + (size_t)b * HD + n] = hnew;
        u16 hbits = f2bf_bits(hnew);
        u16 lbits = f2bf_bits(hnew - bf_bits2f(hbits));
        size_t o = ((size_t)(layer * 2 + ((t + 1) & 1)) * 2) * PLSZ
                 + ((size_t)(n >> 3) * 32 + b) * 8 + (n & 7);
        ht[o] = hbits;
        ht[o + PLSZ] = lbits;
        if (layer == 2) seqout[((size_t)b * TT + t) * HD + n] = hnew;
        if (t == TT - 1) hnout[(size_t)layer * BB * HD + (size_t)b * HD + n] = hnew;
    }
}

// ---------------------------------------------------------------------------
extern "C" void kernel_launch(void* const* d_in, const int* in_sizes, int n_in,
                              void* d_out, int out_size, void* d_ws, size_t ws_size,
                              hipStream_t stream) {
    const float* x   = (const float*)d_in[0];
    const float* h0  = (const float*)d_in[1];
    const float* wih = (const float*)d_in[2];
    const float* whh = (const float*)d_in[3];
    const float* bih = (const float*)d_in[4];
    const float* bhh = (const float*)d_in[5];
    float* out = (float*)d_out;

    char* ws = (char*)d_ws;
    size_t off = 0;
    auto alloc = [&](size_t bytes) -> void* {
        void* p = ws + off;
        off += (bytes + 255) & ~(size_t)255;
        return p;
    };
    // ~235 MB total (proven-safe class; R6's 281MB overflowed)
    u16* gi     = (u16*)alloc((size_t)MTOT * H3 * 2);            // 96 MB
    u16* p0h    = (u16*)alloc((size_t)MTOT * HD * 2);            // 32 MB
    u16* p0l    = (u16*)alloc((size_t)MTOT * HD * 2);            // 32 MB
    u16* wihb   = (u16*)alloc((size_t)H3 * HD * 2);              // 6.3 MB (layer0)
    u16* wslab  = (u16*)alloc((size_t)3 * 256 * 2 * WSL * 2);    // 50.3 MB
    u16* wislab = (u16*)alloc((size_t)2 * 256 * WSL * 2);        // 16.8 MB
    float* hb   = (float*)alloc((size_t)LL * 2 * BB * HD * 4);   // 786 KB
    u16* ht     = (u16*)alloc((size_t)LL * 2 * 2 * PLSZ * 2);    // 786 KB

    // setup
    split_f32_kernel<<<2048, 256, 0, stream>>>(x, p0h, p0l, MTOT * HD / 4);
    tobf_kernel<<<2048, 256, 0, stream>>>(wih, wihb, H3 * HD / 4);
    pack_w_kernel<<<768, 256, 0, stream>>>(whh, wih, wslab, wislab);
    pack_h0_kernel<<<384, 256, 0, stream>>>(h0, hb, ht);

    float* seqbase = out;                        // [B][T][H]
    float* hnbase  = out + (size_t)BB * TT * HD; // [L][B][H]

    // layer-0 input projections (one big GEMM)
    gemm2p_kernel<<<dim3(128 * 24), 256, 0, stream>>>(p0h, p0l, wihb, bih, gi);

    // pipelined recurrence: 514 step kernels
    for (int k = 0; k < TT + LL - 1; ++k)
        gru_step_kernel<<<SGRID, 256, 0, stream>>>(
            wslab, wislab, bih, bhh, gi, hb, ht, seqbase, hnbase, k);
}

// Round 12
// 7638.942 us; speedup vs baseline: 2.9624x; 1.2392x over previous
//
#include <hip/hip_runtime.h>
#include <hip/hip_bf16.h>
#include <stdint.h>

// Problem constants
#define HD   1024
#define BB   32
#define TT   512
#define LL   3
#define H3   3072
#define MTOT (BB*TT)   // 16384

#define PLSZ 32768     // u16 per h plane: 128 kc x 32 b x 8
#define WSL2 12288     // u16 per pad-free weight slab: 128 kc x 12 j x 8

typedef unsigned short u16;
typedef short bf16x8 __attribute__((ext_vector_type(8)));
typedef float f32x4 __attribute__((ext_vector_type(4)));

__device__ __forceinline__ u16 f2bf_bits(float f) {
    __hip_bfloat16 h = __float2bfloat16(f);   // RNE
    return __builtin_bit_cast(u16, h);
}
__device__ __forceinline__ float bf_bits2f(u16 b) {
    return __bfloat162float(__builtin_bit_cast(__hip_bfloat16, b));
}

// 8 consecutive fp32 -> bf16 hi/lo fragments
__device__ __forceinline__ void split8(const f32x4 v0, const f32x4 v1,
                                       bf16x8& hi, bf16x8& lo) {
#pragma unroll
    for (int e = 0; e < 4; ++e) {
        u16 h = f2bf_bits(v0[e]);
        hi[e] = (short)h;
        lo[e] = (short)f2bf_bits(v0[e] - bf_bits2f(h));
        u16 h2 = f2bf_bits(v1[e]);
        hi[4 + e] = (short)h2;
        lo[4 + e] = (short)f2bf_bits(v1[e] - bf_bits2f(h2));
    }
}

// ---------------------------------------------------------------------------
// Split fp32 -> (hi, lo) bf16 planes (row-major, for the big GEMM)
__global__ void split_f32_kernel(const float* __restrict__ in,
                                 u16* __restrict__ hi, u16* __restrict__ lo, int n4) {
    int i = blockIdx.x * blockDim.x + threadIdx.x;
    int stride = gridDim.x * blockDim.x;
    for (; i < n4; i += stride) {
        float4 v = ((const float4*)in)[i];
        ushort4 h, l;
        float f;
        f = v.x; h.x = f2bf_bits(f); l.x = f2bf_bits(f - bf_bits2f(h.x));
        f = v.y; h.y = f2bf_bits(f); l.y = f2bf_bits(f - bf_bits2f(h.y));
        f = v.z; h.z = f2bf_bits(f); l.z = f2bf_bits(f - bf_bits2f(h.z));
        f = v.w; h.w = f2bf_bits(f); l.w = f2bf_bits(f - bf_bits2f(h.w));
        ((ushort4*)hi)[i] = h;
        ((ushort4*)lo)[i] = l;
    }
}

// fp32 -> bf16 (hi only)
__global__ void tobf_kernel(const float* __restrict__ in, u16* __restrict__ out, int n4) {
    int i = blockIdx.x * blockDim.x + threadIdx.x;
    int stride = gridDim.x * blockDim.x;
    for (; i < n4; i += stride) {
        float4 v = ((const float4*)in)[i];
        ushort4 h;
        h.x = f2bf_bits(v.x); h.y = f2bf_bits(v.y);
        h.z = f2bf_bits(v.z); h.w = f2bf_bits(v.w);
        ((ushort4*)out)[i] = h;
    }
}

// ---------------------------------------------------------------------------
// Pack per-(layer,ug) PAD-FREE weight slabs in fragment order [kc][12][8]:
// j = gate*4 + u. whh -> hi plane only (2-pass split-A recipe, same as the
// proven gi GEMM); wih -> hi plane (layers 1,2).
__global__ __launch_bounds__(256) void pack_w_kernel(
    const float* __restrict__ whh, const float* __restrict__ wih,
    u16* __restrict__ wslab, u16* __restrict__ wislab)
{
    const int l  = blockIdx.x >> 8;
    const int ug = blockIdx.x & 255;
    const int n0 = ug * 4;
    const int tid = threadIdx.x;
    const int j = tid >> 4, c16 = tid & 15;
    if (j >= 12) return;
    const size_t rowoff = ((size_t)(j >> 2) * HD + n0 + (j & 3)) * HD;
    const float* wh = whh + (size_t)l * H3 * HD;
    const float* wi = wih + (size_t)l * H3 * HD;
    u16* dh = wslab + ((size_t)l * 256 + ug) * WSL2;
    u16* di = (l > 0) ? (wislab + ((size_t)(l - 1) * 256 + ug) * WSL2) : (u16*)nullptr;
#pragma unroll
    for (int c = 0; c < 8; ++c) {
        int kc = c16 + c * 16;
        f32x4 v0 = *(const f32x4*)(wh + rowoff + kc * 8);
        f32x4 v1 = *(const f32x4*)(wh + rowoff + kc * 8 + 4);
        bf16x8 hi, lo;
        split8(v0, v1, hi, lo);
        *(bf16x8*)(dh + (kc * 12 + j) * 8) = hi;
        if (l > 0) {
            f32x4 u0 = *(const f32x4*)(wi + rowoff + kc * 8);
            f32x4 u1 = *(const f32x4*)(wi + rowoff + kc * 8 + 4);
            bf16x8 ihi, dum;
            split8(u0, u1, ihi, dum);
            *(bf16x8*)(di + (kc * 12 + j) * 8) = ihi;
        }
    }
}

// h0 -> fp32 ping-pong (parity 0) + transposed bf16 hi/lo planes (parity 0)
__global__ void pack_h0_kernel(const float* __restrict__ h0,
                               float* __restrict__ hb, u16* __restrict__ ht) {
    int idx = blockIdx.x * 256 + threadIdx.x;   // 3*32*1024 total
    int l = idx >> 15;
    int rem = idx & 32767;
    int b = rem >> 10, n = rem & 1023;
    float f = h0[idx];
    hb[(size_t)(l * 2) * BB * HD + rem] = f;
    u16 hbits = f2bf_bits(f);
    u16 lbits = f2bf_bits(f - bf_bits2f(hbits));
    size_t o = ((size_t)(l * 2) * 2) * PLSZ + ((size_t)(n >> 3) * 32 + b) * 8 + (n & 7);
    ht[o] = hbits;
    ht[o + PLSZ] = lbits;
}

// ---------------------------------------------------------------------------
// 2-pass split-A bf16 MFMA GEMM (layer-0 input projections) — unchanged, proven.
#define BM 128
#define BN 128
#define BK 32
#define LDSROW 40

__global__ __launch_bounds__(256) void gemm2p_kernel(
    const u16* __restrict__ Ahi, const u16* __restrict__ Alo,
    const u16* __restrict__ Wn,
    const float* __restrict__ bias,
    u16* __restrict__ Cout)
{
    __shared__ u16 sAh[BM * LDSROW];
    __shared__ u16 sAl[BM * LDSROW];
    __shared__ u16 sB [BN * LDSROW];

    const int tid  = threadIdx.x;
    const int lane = tid & 63;
    const int w    = tid >> 6;
    const int wr   = w >> 1, wc = w & 1;
    const int fr   = lane & 15;
    const int kg   = lane >> 4;

    const int bm = blockIdx.x & 127;
    const int bn = blockIdx.x >> 7;
    const int bmBase = bm * BM;
    const int bnBase = bn * BN;

    f32x4 acc[4][4] = {};

    for (int kt = 0; kt < 1024; kt += BK) {
        uint4 ra[2], rl[2], rb[2];
#pragma unroll
        for (int it = 0; it < 2; ++it) {
            int c = it * 256 + tid;
            int row = c >> 2, seg = c & 3;
            size_t ga = (size_t)(bmBase + row) * 1024 + kt + seg * 8;
            ra[it] = *(const uint4*)(Ahi + ga);
            rl[it] = *(const uint4*)(Alo + ga);
            size_t gb = (size_t)(bnBase + row) * 1024 + kt + seg * 8;
            rb[it] = *(const uint4*)(Wn + gb);
        }
        __syncthreads();
#pragma unroll
        for (int it = 0; it < 2; ++it) {
            int c = it * 256 + tid;
            int row = c >> 2, seg = c & 3;
            int lo = row * LDSROW + seg * 8;
            *(uint4*)(sAh + lo) = ra[it];
            *(uint4*)(sAl + lo) = rl[it];
            *(uint4*)(sB  + lo) = rb[it];
        }
        __syncthreads();

        bf16x8 fah[4], fal[4], fb[4];
#pragma unroll
        for (int mi = 0; mi < 4; ++mi) {
            int r = wr * 64 + mi * 16 + fr;
            fah[mi] = *(const bf16x8*)(sAh + r * LDSROW + kg * 8);
            fal[mi] = *(const bf16x8*)(sAl + r * LDSROW + kg * 8);
        }
#pragma unroll
        for (int ni = 0; ni < 4; ++ni) {
            int r = wc * 64 + ni * 16 + fr;
            fb[ni] = *(const bf16x8*)(sB + r * LDSROW + kg * 8);
        }
#pragma unroll
        for (int mi = 0; mi < 4; ++mi)
#pragma unroll
            for (int ni = 0; ni < 4; ++ni) {
                acc[mi][ni] = __builtin_amdgcn_mfma_f32_16x16x32_bf16(fah[mi], fb[ni], acc[mi][ni], 0, 0, 0);
                acc[mi][ni] = __builtin_amdgcn_mfma_f32_16x16x32_bf16(fal[mi], fb[ni], acc[mi][ni], 0, 0, 0);
            }
    }

#pragma unroll
    for (int mi = 0; mi < 4; ++mi)
#pragma unroll
        for (int ni = 0; ni < 4; ++ni) {
            int n = bnBase + wc * 64 + ni * 16 + fr;
            float bv = bias[n];
#pragma unroll
            for (int r = 0; r < 4; ++r) {
                int m = bmBase + wr * 64 + mi * 16 + kg * 4 + r;
                int b_ = m >> 9, t_ = m & 511;           // m = b*512 + t
                Cout[(size_t)(t_ * BB + b_) * H3 + n] = f2bf_bits(acc[mi][ni][r] + bv);
            }
        }
}

// ---------------------------------------------------------------------------
// Pipelined per-step kernel. Kernel k: layer0 step k, layer1 k-1, layer2 k-2.
// Kernel boundaries provide all cross-XCD ordering (no custom coherence).
// Grid 768 = 3 layers x 256 ug (4 units); 256 threads = 4 waves (K-split 256).
// Pad-free slabs (lanes arow>=12 contribute zero B fragments); gh and gi both
// 2-pass split-A (A hi/lo bf16 x W hi bf16) — the recipe proven in the GEMM.
#define SGRID 768

__global__ __launch_bounds__(256) void gru_step_kernel(
    const u16* __restrict__ wslab,   // [3][256][WSL2] whh hi
    const u16* __restrict__ wislab,  // [2][256][WSL2] wih hi (layers 1,2)
    const float* __restrict__ bih, const float* __restrict__ bhh,  // [L][3H]
    const u16* __restrict__ gi0,     // [T][B][3H] (layer0, incl b_ih)
    float* __restrict__ hb,          // [3][2][32][1024] fp32
    u16* __restrict__ ht,            // [3][2][2][PLSZ] transposed planes
    float* __restrict__ seqout, float* __restrict__ hnout, int k)
{
    const int layer = blockIdx.x >> 8;
    const int t = k - layer;
    if (t < 0 || t >= TT) return;
    const int ug = blockIdx.x & 255;
    const int n0 = ug * 4;
    const int tid = threadIdx.x, lane = tid & 63, w = tid >> 6;
    const int arow = lane & 15, akg = lane >> 4;

    __shared__ float Cp[4][2][2][16][16];   // [wave][src][m][row][col] 16KB

    const int xl = (layer > 0) ? layer - 1 : 0;
    const u16* hsH = ht + ((size_t)(layer * 2 + (t & 1)) * 2) * PLSZ;
    const u16* hsL = hsH + PLSZ;
    const u16* xsH = ht + ((size_t)(xl * 2 + ((t + 1) & 1)) * 2) * PLSZ;
    const u16* xsL = xsH + PLSZ;
    const u16* whH = wslab + ((size_t)layer * 256 + ug) * WSL2;
    const u16* wiH = wislab + ((size_t)xl * 256 + ug) * WSL2;

    // layer-0 gi early loads (latency hidden under the MFMA loop)
    float gi_0 = 0.f, gi_1 = 0.f, gi_2 = 0.f;
    if (layer == 0 && tid < 128) {
        const u16* gp = gi0 + (size_t)(t * BB + (tid >> 2)) * H3 + n0 + (tid & 3);
        gi_0 = bf_bits2f(gp[0]);
        gi_1 = bf_bits2f(gp[HD]);
        gi_2 = bf_bits2f(gp[2 * HD]);
    }

    f32x4 agh[2] = {};
    f32x4 agx[2] = {};

#pragma unroll
    for (int kt = 0; kt < 8; ++kt) {
        const int kc = w * 32 + kt * 4 + akg;
        const int aoff = (kc * 32 + arow) * 8;     // m=0; m=1 at +128
        bf16x8 a0h = *(const bf16x8*)(hsH + aoff);
        bf16x8 a0l = *(const bf16x8*)(hsL + aoff);
        bf16x8 a1h = *(const bf16x8*)(hsH + aoff + 128);
        bf16x8 a1l = *(const bf16x8*)(hsL + aoff + 128);
        bf16x8 bh = {}, bi = {};
        if (arow < 12) {
            bh = *(const bf16x8*)(whH + (kc * 12 + arow) * 8);
            if (layer > 0) bi = *(const bf16x8*)(wiH + (kc * 12 + arow) * 8);
        }
        agh[0] = __builtin_amdgcn_mfma_f32_16x16x32_bf16(a0h, bh, agh[0], 0, 0, 0);
        agh[0] = __builtin_amdgcn_mfma_f32_16x16x32_bf16(a0l, bh, agh[0], 0, 0, 0);
        agh[1] = __builtin_amdgcn_mfma_f32_16x16x32_bf16(a1h, bh, agh[1], 0, 0, 0);
        agh[1] = __builtin_amdgcn_mfma_f32_16x16x32_bf16(a1l, bh, agh[1], 0, 0, 0);
        if (layer > 0) {
            bf16x8 x0h = *(const bf16x8*)(xsH + aoff);
            bf16x8 x0l = *(const bf16x8*)(xsL + aoff);
            bf16x8 x1h = *(const bf16x8*)(xsH + aoff + 128);
            bf16x8 x1l = *(const bf16x8*)(xsL + aoff + 128);
            agx[0] = __builtin_amdgcn_mfma_f32_16x16x32_bf16(x0h, bi, agx[0], 0, 0, 0);
            agx[0] = __builtin_amdgcn_mfma_f32_16x16x32_bf16(x0l, bi, agx[0], 0, 0, 0);
            agx[1] = __builtin_amdgcn_mfma_f32_16x16x32_bf16(x1h, bi, agx[1], 0, 0, 0);
            agx[1] = __builtin_amdgcn_mfma_f32_16x16x32_bf16(x1l, bi, agx[1], 0, 0, 0);
        }
    }

    // Per-wave partial slices (no atomics).
#pragma unroll
    for (int m = 0; m < 2; ++m)
#pragma unroll
        for (int i = 0; i < 4; ++i)
            Cp[w][0][m][akg * 4 + i][arow] = agh[m][i];
    if (layer > 0) {
#pragma unroll
        for (int m = 0; m < 2; ++m)
#pragma unroll
            for (int i = 0; i < 4; ++i)
                Cp[w][1][m][akg * 4 + i][arow] = agx[m][i];
    }
    __syncthreads();

    // Gate phase: 128 threads, one (b,u) each
    if (tid < 128) {
        const int b = tid >> 2, u = tid & 3;
        const int m = b >> 4, r = b & 15;
        const int n = n0 + u;
        float gh0 = 0.f, gh1 = 0.f, gh2 = 0.f;
#pragma unroll
        for (int ww = 0; ww < 4; ++ww) {
            gh0 += Cp[ww][0][m][r][u];
            gh1 += Cp[ww][0][m][r][4 + u];
            gh2 += Cp[ww][0][m][r][8 + u];
        }
        if (layer > 0) {
            float q0 = 0.f, q1 = 0.f, q2 = 0.f;
#pragma unroll
            for (int ww = 0; ww < 4; ++ww) {
                q0 += Cp[ww][1][m][r][u];
                q1 += Cp[ww][1][m][r][4 + u];
                q2 += Cp[ww][1][m][r][8 + u];
            }
            gi_0 = q0 + bih[layer * H3 + n];
            gi_1 = q1 + bih[layer * H3 + HD + n];
            gi_2 = q2 + bih[layer * H3 + 2 * HD + n];
        }
        const float bh0 = bhh[layer * H3 + n];
        const float bh1 = bhh[layer * H3 + HD + n];
        const float bh2 = bhh[layer * H3 + 2 * HD + n];
        const float hp = hb[(size_t)(layer * 2 + (t & 1)) * BB * HD + (size_t)b * HD + n];
        float rg = 1.f / (1.f + expf(-(gi_0 + gh0 + bh0)));
        float zg = 1.f / (1.f + expf(-(gi_1 + gh1 + bh1)));
        float ng = tanhf(gi_2 + rg * (gh2 + bh2));
        float hnew = (1.f - zg) * ng + zg * hp;
        hb[(size_t)(layer * 2 + ((t + 1) & 1)) * BB * HD + (size_t)b * HD + n] = hnew;
        u16 hbits = f2bf_bits(hnew);
        u16 lbits = f2bf_bits(hnew - bf_bits2f(hbits));
        size_t o = ((size_t)(layer * 2 + ((t + 1) & 1)) * 2) * PLSZ
                 + ((size_t)(n >> 3) * 32 + b) * 8 + (n & 7);
        ht[o] = hbits;
        ht[o + PLSZ] = lbits;
        if (layer == 2) seqout[((size_t)b * TT + t) * HD + n] = hnew;
        if (t == TT - 1) hnout[(size_t)layer * BB * HD + (size_t)b * HD + n] = hnew;
    }
}

// ---------------------------------------------------------------------------
extern "C" void kernel_launch(void* const* d_in, const int* in_sizes, int n_in,
                              void* d_out, int out_size, void* d_ws, size_t ws_size,
                              hipStream_t stream) {
    const float* x   = (const float*)d_in[0];
    const float* h0  = (const float*)d_in[1];
    const float* wih = (const float*)d_in[2];
    const float* whh = (const float*)d_in[3];
    const float* bih = (const float*)d_in[4];
    const float* bhh = (const float*)d_in[5];
    float* out = (float*)d_out;

    char* ws = (char*)d_ws;
    size_t off = 0;
    auto alloc = [&](size_t bytes) -> void* {
        void* p = ws + off;
        off += (bytes + 255) & ~(size_t)255;
        return p;
    };
    // ~200 MB total
    u16* gi     = (u16*)alloc((size_t)MTOT * H3 * 2);            // 96 MB
    u16* p0h    = (u16*)alloc((size_t)MTOT * HD * 2);            // 32 MB
    u16* p0l    = (u16*)alloc((size_t)MTOT * HD * 2);            // 32 MB
    u16* wihb   = (u16*)alloc((size_t)H3 * HD * 2);              // 6.3 MB (layer0)
    u16* wslab  = (u16*)alloc((size_t)3 * 256 * WSL2 * 2);       // 18.9 MB
    u16* wislab = (u16*)alloc((size_t)2 * 256 * WSL2 * 2);       // 12.6 MB
    float* hb   = (float*)alloc((size_t)LL * 2 * BB * HD * 4);   // 786 KB
    u16* ht     = (u16*)alloc((size_t)LL * 2 * 2 * PLSZ * 2);    // 786 KB

    // setup
    split_f32_kernel<<<2048, 256, 0, stream>>>(x, p0h, p0l, MTOT * HD / 4);
    tobf_kernel<<<2048, 256, 0, stream>>>(wih, wihb, H3 * HD / 4);
    pack_w_kernel<<<768, 256, 0, stream>>>(whh, wih, wslab, wislab);
    pack_h0_kernel<<<384, 256, 0, stream>>>(h0, hb, ht);

    float* seqbase = out;                        // [B][T][H]
    float* hnbase  = out + (size_t)BB * TT * HD; // [L][B][H]

    // layer-0 input projections (one big GEMM)
    gemm2p_kernel<<<dim3(128 * 24), 256, 0, stream>>>(p0h, p0l, wihb, bih, gi);

    // pipelined recurrence: 514 step kernels
    for (int k = 0; k < TT + LL - 1; ++k)
        gru_step_kernel<<<SGRID, 256, 0, stream>>>(
            wslab, wislab, bih, bhh, gi, hb, ht, seqbase, hnbase, k);
}